// Round 10
// baseline (403.106 us; speedup 1.0000x reference)
//
#include <hip/hip_runtime.h>

// FastGuidedFilter: 24 planes (8x3) of 1024x1024 f32, r=8 (17x17 clipped box).
//
// Two barrier-free full-row sweep kernels through d_ws (A,b planes, 201 MB).
// 64-thread (1-wave) blocks, wave = full 1024-col row (16 aligned cols/lane),
// CH=8 output rows per wave, 3072 waves per kernel.
//
// K1 (fgf_ab): vertical-sums-first. Per step ALL FOUR row loads (lead x,y +
// trail x,y; clamped, validity as 0/1 scale) are issued before any FMA, so
// each step pays ONE memory latency, and the long window/A,b/store VALU
// stretch overlaps the next step's loads. Horizontal 17-tap window only at
// the 8 output steps via win17_nbr (prefix/suffix + 16 independent shfl+-1).
// K2 (fgf_out): round-4 body verbatim (measured 87 us, ~4.7 TB/s): per-lane
// 32-col span loads + local prefix-chain windows, no shuffles.
//
// Fallback: if ws_size < 201 MB, run the round-1 fused single kernel.

#define HH 1024
#define WW 1024
#define NPLANES 24
#define RAD 8
#define CH 8
#define NCHROW (HH / CH)                 // 128 row-chunks per plane
#define NCHUNKS (NPLANES * NCHROW)       // 3072 single-wave blocks

// per-column horizontal count reciprocal: interior = 1/17; only lanes 0/63
// have clipped columns; m is compile-time.
__device__ __forceinline__ float invCCf(int lane, int m) {
    const float cL = (m < 8) ? (1.f / (float)(m + 9)) : (1.f / 17.f);
    const float cR = (m > 7) ? (1.f / (float)(24 - m)) : (1.f / 17.f);
    float v = 1.f / 17.f;
    v = (lane == 0)  ? cL : v;
    v = (lane == 63) ? cR : v;
    return v;
}

// Load the lane's 16 aligned cols of one (valid, clamped) row.
__device__ __forceinline__ void load16(const float* __restrict__ rowp, int lane,
                                       float* __restrict__ d) {
    const float4* p = (const float4*)rowp + lane * 4;
#pragma unroll
    for (int k = 0; k < 4; ++k) {
        float4 a = p[k];
        d[4 * k + 0] = a.x; d[4 * k + 1] = a.y;
        d[4 * k + 2] = a.z; d[4 * k + 3] = a.w;
    }
}

// Load 32 cols [16*lane-8, 16*lane+24) of one row; OOB cols -> 0.
__device__ __forceinline__ void load32(const float* __restrict__ rowp, int lane,
                                       float* __restrict__ d) {
    const int c0 = lane * 16 - 8;
#pragma unroll
    for (int k = 0; k < 8; ++k) {
        int c = c0 + 4 * k;
        float4 a = make_float4(0.f, 0.f, 0.f, 0.f);
        if ((unsigned)c < (unsigned)WW) a = *(const float4*)(rowp + c);
        d[4 * k + 0] = a.x; d[4 * k + 1] = a.y;
        d[4 * k + 2] = a.z; d[4 * k + 3] = a.w;
    }
}

// acc[m] += SIGN * sum(v[m .. m+16])   (17-tap window, local indices)
template <int SIGN>
__device__ __forceinline__ void accum_hwin(const float* __restrict__ v,
                                           float* __restrict__ acc) {
    float L[16], R[16];
    L[0] = v[0];
#pragma unroll
    for (int m = 1; m < 16; ++m) L[m] = L[m - 1] + v[m];
    R[0] = v[16];
#pragma unroll
    for (int m = 1; m < 16; ++m) R[m] = R[m - 1] + v[16 + m];
    const float L15 = L[15];
#pragma unroll
    for (int m = 0; m < 16; ++m) {
        float w = (m ? (L15 - L[m - 1]) : L15) + R[m];
        acc[m] += (SIGN > 0) ? w : -w;
    }
}

// 17-tap zero-padded horizontal window of s[] (lane owns cols 16l..16l+15).
__device__ __forceinline__ void win17_nbr(const float* __restrict__ s, int lane,
                                          float* __restrict__ w) {
    float P[16];
    P[0] = s[0];
#pragma unroll
    for (int m = 1; m < 16; ++m) P[m] = P[m - 1] + s[m];
    float S[8];                       // S[k] = sum s[8+k .. 15]
    S[7] = s[15];
#pragma unroll
    for (int k = 6; k >= 0; --k) S[k] = S[k + 1] + s[8 + k];
    float SL[8], PR[8];
#pragma unroll
    for (int k = 0; k < 8; ++k) SL[k] = __shfl_up(S[k], 1, 64);
#pragma unroll
    for (int k = 0; k < 8; ++k) PR[k] = __shfl_down(P[k], 1, 64);
    const bool hasL = (lane > 0), hasR = (lane < 63);
#pragma unroll
    for (int m = 0; m < 8; ++m) w[m] = (hasL ? SL[m] : 0.f) + P[m + 8];
    w[8] = P[15] + (hasR ? PR[0] : 0.f);
#pragma unroll
    for (int m = 9; m < 16; ++m) w[m] = (P[15] - P[m - 9]) + (hasR ? PR[m - 8] : 0.f);
}

__global__ __launch_bounds__(64)
void fgf_ab(const float* __restrict__ x, const float* __restrict__ y,
            float* __restrict__ Aw, float* __restrict__ bw)
{
    const int lane  = threadIdx.x;
    const int chunk = blockIdx.x;
    const int p  = chunk / NCHROW;
    const int R0 = (chunk - p * NCHROW) * CH;
    const size_t po = (size_t)p * HH * WW;
    const float* xp = x + po;
    const float* yp = y + po;
    float* Ap = Aw + po;
    float* bp = bw + po;

    float vsx[16], vsy[16], vsxy[16], vsxx[16];
#pragma unroll
    for (int m = 0; m < 16; ++m) { vsx[m] = vsy[m] = vsxy[m] = vsxx[m] = 0.f; }

    // warmup: rows R0-8 .. R0+7, processed in pairs with all 4 loads grouped
#pragma unroll 1
    for (int s = 0; s < 2 * RAD; s += 2) {
        const int r0 = R0 - RAD + s;
        const int r1 = r0 + 1;
        const float s0 = (r0 >= 0) ? 1.f : 0.f;
        const float s1 = (r1 >= 0) ? 1.f : 0.f;
        const int rs0 = (r0 >= 0) ? r0 : 0;
        const int rs1 = (r1 >= 0) ? r1 : 0;
        float xa[16], ya[16], xb[16], yb[16];
        load16(xp + (size_t)rs0 * WW, lane, xa);
        load16(yp + (size_t)rs0 * WW, lane, ya);
        load16(xp + (size_t)rs1 * WW, lane, xb);
        load16(yp + (size_t)rs1 * WW, lane, yb);
#pragma unroll
        for (int m = 0; m < 16; ++m) {
            float t0 = s0 * xa[m], u0 = s0 * ya[m];
            float t1 = s1 * xb[m], u1 = s1 * yb[m];
            vsx[m] += t0 + t1;
            vsy[m] += u0 + u1;
            vsxy[m] = fmaf(t0, ya[m], vsxy[m]);
            vsxy[m] = fmaf(t1, yb[m], vsxy[m]);
            vsxx[m] = fmaf(t0, xa[m], vsxx[m]);
            vsxx[m] = fmaf(t1, xb[m], vsxx[m]);
        }
    }

    for (int t = 0; t < CH; ++t) {
        const int i = R0 + t;
        const int rl = i + RAD;
        const float sl = (rl < HH) ? 1.f : 0.f;
        const int rls = (rl < HH) ? rl : (HH - 1);
        const int rt = i - RAD - 1;
        const float st = (t > 0 && rt >= 0) ? 1.f : 0.f;
        const int rts = (rt >= 0) ? rt : 0;

        // ALL loads for this step issued together (one latency per step)
        float xl[16], yl[16], xt[16], yt[16];
        load16(xp + (size_t)rls * WW, lane, xl);
        load16(yp + (size_t)rls * WW, lane, yl);
        load16(xp + (size_t)rts * WW, lane, xt);
        load16(yp + (size_t)rts * WW, lane, yt);

#pragma unroll
        for (int m = 0; m < 16; ++m) {
            float tl = sl * xl[m], ul = sl * yl[m];
            float tt = st * xt[m], ut = st * yt[m];
            vsx[m] += tl - tt;
            vsy[m] += ul - ut;
            vsxy[m] = fmaf(tl, yl[m], vsxy[m]);
            vsxy[m] = fmaf(-tt, yt[m], vsxy[m]);
            vsxx[m] = fmaf(tl, xl[m], vsxx[m]);
            vsxx[m] = fmaf(-tt, xt[m], vsxx[m]);
        }

        // output row i: 4 horizontal windows + A,b (staged, buffers reused)
        const float invCR = 1.f / (float)(min(i + RAD, HH - 1) - max(i - RAD, 0) + 1);
        float w[16], mxv[16], myv[16], covv[16];
        win17_nbr(vsx, lane, w);
#pragma unroll
        for (int m = 0; m < 16; ++m) mxv[m] = w[m] * (invCR * invCCf(lane, m));
        win17_nbr(vsy, lane, w);
#pragma unroll
        for (int m = 0; m < 16; ++m) myv[m] = w[m] * (invCR * invCCf(lane, m));
        win17_nbr(vsxy, lane, w);
#pragma unroll
        for (int m = 0; m < 16; ++m)
            covv[m] = w[m] * (invCR * invCCf(lane, m)) - mxv[m] * myv[m];
        win17_nbr(vsxx, lane, w);
#pragma unroll
        for (int m = 0; m < 16; ++m) {
            float vr = w[m] * (invCR * invCCf(lane, m)) - mxv[m] * mxv[m];
            float A  = covv[m] / (vr + 1e-8f);
            covv[m] = A;                        // covv -> A
            myv[m]  = myv[m] - A * mxv[m];      // myv  -> b
        }
        float4* Ar = (float4*)(Ap + (size_t)i * WW) + lane * 4;
        float4* Br = (float4*)(bp + (size_t)i * WW) + lane * 4;
#pragma unroll
        for (int k = 0; k < 4; ++k) {
            Ar[k] = make_float4(covv[4*k+0], covv[4*k+1], covv[4*k+2], covv[4*k+3]);
            Br[k] = make_float4(myv[4*k+0],  myv[4*k+1],  myv[4*k+2],  myv[4*k+3]);
        }
    }
}

// K2: round-4 body verbatim (best measured: 87 us, ~4.7 TB/s).
__global__ __launch_bounds__(64)
void fgf_out(const float* __restrict__ Aw, const float* __restrict__ bw,
             const float* __restrict__ x, float* __restrict__ out)
{
    const int lane = threadIdx.x;
    const int job  = blockIdx.x;
    const int p    = job / NCHROW;
    const int R0   = (job - p * NCHROW) * CH;
    const size_t po = (size_t)p * HH * WW;
    const float* Apl = Aw + po;
    const float* bpl = bw + po;
    const float* xp  = x + po;
    float* op = out + po;

    float invCC[16];
#pragma unroll
    for (int m = 0; m < 16; ++m) {
        int j = lane * 16 + m;
        int c = min(j + RAD, WW - 1) - max(j - RAD, 0) + 1;
        invCC[m] = 1.f / (float)c;
    }

    float sA[16], sB[16];
#pragma unroll
    for (int m = 0; m < 16; ++m) { sA[m] = 0.f; sB[m] = 0.f; }

    float v[32];

    for (int r = R0 - RAD; r <= R0 + CH - 1 + RAD; ++r) {
        if ((unsigned)r < (unsigned)HH) {
            load32(Apl + (size_t)r * WW, lane, v);
            accum_hwin<+1>(v, sA);
            load32(bpl + (size_t)r * WW, lane, v);
            accum_hwin<+1>(v, sB);
        }
        const int rt = r - (2 * RAD + 1);
        if (rt >= R0 - RAD && rt >= 0) {
            load32(Apl + (size_t)rt * WW, lane, v);
            accum_hwin<-1>(v, sA);
            load32(bpl + (size_t)rt * WW, lane, v);
            accum_hwin<-1>(v, sB);
        }

        const int i = r - RAD;
        if (i >= R0) {
            float cR = (float)(min(i + RAD, HH - 1) - max(i - RAD, 0) + 1);
            float invCR = 1.f / cR;
            const float4* xrow = (const float4*)(xp + (size_t)i * WW);
            float4* Orow = (float4*)(op + (size_t)i * WW);
#pragma unroll
            for (int k = 0; k < 4; ++k) {
                float4 xv4 = xrow[lane * 4 + k];
                float4 o;
                float invN0 = invCR * invCC[k*4+0];
                float invN1 = invCR * invCC[k*4+1];
                float invN2 = invCR * invCC[k*4+2];
                float invN3 = invCR * invCC[k*4+3];
                o.x = (sA[k*4+0] * invN0) * xv4.x + sB[k*4+0] * invN0;
                o.y = (sA[k*4+1] * invN1) * xv4.y + sB[k*4+1] * invN1;
                o.z = (sA[k*4+2] * invN2) * xv4.z + sB[k*4+2] * invN2;
                o.w = (sA[k*4+3] * invN3) * xv4.w + sB[k*4+3] * invN3;
                Orow[lane * 4 + k] = o;
            }
        }
    }
}

// ---------------- fallback: round-1 fused kernel (if ws too small) ----------------
#define TH 32
#define TW 64
#define RAWROWS (TH + 32)
#define RAWCOLS (TW + 32)
#define RAWSTR  (RAWCOLS + 1)
#define HROWS RAWROWS
#define HCOLS (TW + 16)
#define FHSTR  (HCOLS + 1)
#define BROWS (TH + 16)
#define STR2  (TW + 1)
#define REGA 15552
#define REGB 20736
#define SMEM_FLOATS (REGA + REGB)
#define SMEM_BYTES  (SMEM_FLOATS * 4)

extern "C" __global__ __launch_bounds__(256)
void fgf_fused(const float* __restrict__ x, const float* __restrict__ y,
               float* __restrict__ out)
{
    extern __shared__ float smem[];
    float* RA = smem;
    float* RB = smem + REGA;

    const int tid = threadIdx.x;
    const int tc = blockIdx.x;
    const int tr = blockIdx.y;
    const int p  = blockIdx.z;
    const int R0 = tr * TH;
    const int C0 = tc * TW;
    const size_t planeOff = (size_t)p * HH * WW;
    const float* xp = x + planeOff;
    const float* yp = y + planeOff;
    float* op = out + planeOff;

    float* rawx = RA;
    float* rawy = RA + RAWROWS * RAWSTR;

    for (int idx = tid; idx < RAWROWS * RAWCOLS; idx += 256) {
        int rr = idx / RAWCOLS;
        int cc = idx - rr * RAWCOLS;
        int gi = R0 - 16 + rr;
        int gj = C0 - 16 + cc;
        float vx = 0.f, vy = 0.f;
        if (gi >= 0 && gi < HH && gj >= 0 && gj < WW) {
            size_t g = (size_t)gi * WW + gj;
            vx = xp[g]; vy = yp[g];
        }
        rawx[rr * RAWSTR + cc] = vx;
        rawy[rr * RAWSTR + cc] = vy;
    }
    __syncthreads();

    {
        const int q   = tid >> 6;
        const int row = tid & 63;
        const float* rx = rawx + row * RAWSTR;
        const float* ry = rawy + row * RAWSTR;
        float* hq = RB + (q * HROWS + row) * FHSTR;
#define H1_SCAN(VAL_EXPR)                                    \
        {                                                    \
            float s = 0.f;                                   \
            for (int k = 0; k < 16; ++k) { int c = k; s += (VAL_EXPR); } \
            for (int j = 0; j < HCOLS; ++j) {                \
                { int c = j + 16; s += (VAL_EXPR); }         \
                hq[j] = s;                                   \
                { int c = j; s -= (VAL_EXPR); }              \
            }                                                \
        }
        if (q == 0)      H1_SCAN(rx[c])
        else if (q == 1) H1_SCAN(ry[c])
        else if (q == 2) H1_SCAN(rx[c] * ry[c])
        else             H1_SCAN(rx[c] * rx[c])
#undef H1_SCAN
    }
    __syncthreads();

    for (int item = tid; item < 4 * HCOLS; item += 256) {
        int q   = item / HCOLS;
        int col = item - q * HCOLS;
        const float* hq = RB + q * HROWS * FHSTR + col;
        float* bq = RA + q * BROWS * FHSTR + col;
        float s = 0.f;
        for (int k = 0; k < 16; ++k) s += hq[k * FHSTR];
        for (int i = 0; i < BROWS; ++i) {
            s += hq[(i + 16) * FHSTR];
            bq[i * FHSTR] = s;
            s -= hq[i * FHSTR];
        }
    }
    __syncthreads();

    for (int it = tid; it < BROWS * HCOLS; it += 256) {
        int ii = it / HCOLS;
        int jj = it - ii * HCOLS;
        int gi = R0 - 8 + ii;
        int gj = C0 - 8 + jj;
        float Av = 0.f, bv = 0.f;
        if (gi >= 0 && gi < HH && gj >= 0 && gj < WW) {
            float cntR = (float)(min(gi + RAD, HH - 1) - max(gi - RAD, 0) + 1);
            float cntC = (float)(min(gj + RAD, WW - 1) - max(gj - RAD, 0) + 1);
            float invN = 1.f / (cntR * cntC);
            float sxv  = RA[0 * BROWS * FHSTR + ii * FHSTR + jj];
            float syv  = RA[1 * BROWS * FHSTR + ii * FHSTR + jj];
            float sxyv = RA[2 * BROWS * FHSTR + ii * FHSTR + jj];
            float sxxv = RA[3 * BROWS * FHSTR + ii * FHSTR + jj];
            float mx  = sxv * invN;
            float my  = syv * invN;
            float cv  = sxyv * invN - mx * my;
            float vr  = sxxv * invN - mx * mx;
            Av = cv / (vr + 1e-8f);
            bv = my - Av * mx;
        }
        RB[ii * FHSTR + jj] = Av;
        RB[BROWS * FHSTR + ii * FHSTR + jj] = bv;
    }
    __syncthreads();

    if (tid < 2 * BROWS) {
        int q   = tid / BROWS;
        int row = tid - q * BROWS;
        const float* src = RB + q * BROWS * FHSTR + row * FHSTR;
        float* dst = RA + (q * BROWS + row) * STR2;
        float s = 0.f;
        for (int k = 0; k < 16; ++k) s += src[k];
        for (int j = 0; j < TW; ++j) {
            s += src[j + 16];
            dst[j] = s;
            s -= src[j];
        }
    }
    __syncthreads();

    if (tid < 2 * TW) {
        int q   = tid >> 6;
        int col = tid & 63;
        const float* src = RA + q * BROWS * STR2 + col;
        float* dst = RB + q * TH * STR2 + col;
        float s = 0.f;
        for (int k = 0; k < 16; ++k) s += src[k * STR2];
        for (int i = 0; i < TH; ++i) {
            s += src[(i + 16) * STR2];
            dst[i * STR2] = s;
            s -= src[i * STR2];
        }
    }
    __syncthreads();

    for (int it = tid; it < TH * TW; it += 256) {
        int ii = it >> 6;
        int jj = it & 63;
        int gi = R0 + ii;
        int gj = C0 + jj;
        float cntR = (float)(min(gi + RAD, HH - 1) - max(gi - RAD, 0) + 1);
        float cntC = (float)(min(gj + RAD, WW - 1) - max(gj - RAD, 0) + 1);
        float invN = 1.f / (cntR * cntC);
        float mA = RB[ii * STR2 + jj] * invN;
        float mb = RB[TH * STR2 + ii * STR2 + jj] * invN;
        size_t g = (size_t)gi * WW + gj;
        op[g] = mA * xp[g] + mb;
    }
}

extern "C" void kernel_launch(void* const* d_in, const int* in_sizes, int n_in,
                              void* d_out, int out_size, void* d_ws, size_t ws_size,
                              hipStream_t stream) {
    const float* x = (const float*)d_in[0];
    const float* y = (const float*)d_in[1];
    float* out = (float*)d_out;

    const size_t planeFloats = (size_t)NPLANES * HH * WW;   // 24M
    const size_t wsNeed = 2 * planeFloats * sizeof(float);  // 201.3 MB

    if (ws_size >= wsNeed) {
        float* Aw = (float*)d_ws;
        float* bw = Aw + planeFloats;
        fgf_ab<<<dim3(NCHUNKS), 64, 0, stream>>>(x, y, Aw, bw);
        fgf_out<<<dim3(NCHUNKS), 64, 0, stream>>>(Aw, bw, x, out);
    } else {
        hipFuncSetAttribute((const void*)fgf_fused,
                            hipFuncAttributeMaxDynamicSharedMemorySize, SMEM_BYTES);
        dim3 grid(WW / TW, HH / TH, NPLANES);
        fgf_fused<<<grid, 256, SMEM_BYTES, stream>>>(x, y, out);
    }
}

// Round 12
// 311.419 us; speedup vs baseline: 1.2944x; 1.2944x over previous
//
#include <hip/hip_runtime.h>

// FastGuidedFilter: 24 planes (8x3) of 1024x1024 f32, r=8 (17x17 clipped box).
//
// SINGLE fused sweep kernel — no workspace, no LDS, no barriers.
// Wave = full 1024-col row (16 aligned cols/lane), CH=8 output rows/wave,
// 3072 single-wave blocks.
//
// Two register-resident stage-1 vertical-sum sets per lane:
//   LEAD set: window centered at A-row jl = i+8  -> produces A,b(jl), added
//             into vertical A,b running sums vA,vB.
//   TRAIL set: lags 17 rows (jt = i-9) -> recomputes A,b(jt) for subtraction
//             from vA,vB (avoids a 17-row A,b ring).
// Row sharing: lead-sub and trail-add both use row i-1 (one load).
// Horizontal 17-tap windows via win17_nbr: per-lane prefix/suffix + 16
// independent shfl(+-1); zero-padded edges; clipped counts are compile-time
// selects (only lanes 0/63 clipped).
// Output: out(i) = (winH(vA)*invN) * x(i) + winH(vB)*invN.
//
// NaN-safety (round-11 postmortem): invCRf clamps its count to >=1 (j=-9 gave
// 1/0=inf; 0*inf=NaN leaked through fma masks), and the trail subtraction is
// a wave-uniform BRANCH, not a 0/1 mask.

#define HH 1024
#define WW 1024
#define NPLANES 24
#define RAD 8
#define CH 8
#define NCHROW (HH / CH)                 // 128 row-chunks per plane
#define NCHUNKS (NPLANES * NCHROW)       // 3072 single-wave blocks

// per-column horizontal count reciprocal: interior = 1/17; only lanes 0/63
// have clipped columns; m is compile-time.
__device__ __forceinline__ float invCCf(int lane, int m) {
    const float cL = (m < 8) ? (1.f / (float)(m + 9)) : (1.f / 17.f);
    const float cR = (m > 7) ? (1.f / (float)(24 - m)) : (1.f / 17.f);
    float v = 1.f / 17.f;
    v = (lane == 0)  ? cL : v;
    v = (lane == 63) ? cR : v;
    return v;
}

// per-row vertical count reciprocal (clipped box), clamped to >=1 so that
// out-of-range (masked) positions stay finite.
__device__ __forceinline__ float invCRf(int j) {
    int c = min(j + RAD, HH - 1) - max(j - RAD, 0) + 1;
    c = max(c, 1);
    return 1.f / (float)c;
}

// Load the lane's 16 aligned cols of one (valid, clamped) row.
__device__ __forceinline__ void load16(const float* __restrict__ rowp, int lane,
                                       float* __restrict__ d) {
    const float4* p = (const float4*)rowp + lane * 4;
#pragma unroll
    for (int k = 0; k < 4; ++k) {
        float4 a = p[k];
        d[4 * k + 0] = a.x; d[4 * k + 1] = a.y;
        d[4 * k + 2] = a.z; d[4 * k + 3] = a.w;
    }
}

// 17-tap zero-padded horizontal window of s[] (lane owns cols 16l..16l+15).
// w[m] = sum s over cols [j-8, j+8] ∩ [0,1024), j = 16*lane+m.
__device__ __forceinline__ void win17_nbr(const float* __restrict__ s, int lane,
                                          float* __restrict__ w) {
    float P[16];
    P[0] = s[0];
#pragma unroll
    for (int m = 1; m < 16; ++m) P[m] = P[m - 1] + s[m];
    float S[8];                       // S[k] = sum s[8+k .. 15]
    S[7] = s[15];
#pragma unroll
    for (int k = 6; k >= 0; --k) S[k] = S[k + 1] + s[8 + k];
    float SL[8], PR[8];
#pragma unroll
    for (int k = 0; k < 8; ++k) SL[k] = __shfl_up(S[k], 1, 64);
#pragma unroll
    for (int k = 0; k < 8; ++k) PR[k] = __shfl_down(P[k], 1, 64);
    const bool hasL = (lane > 0), hasR = (lane < 63);
#pragma unroll
    for (int m = 0; m < 8; ++m) w[m] = (hasL ? SL[m] : 0.f) + P[m + 8];
    w[8] = P[15] + (hasR ? PR[0] : 0.f);
#pragma unroll
    for (int m = 9; m < 16; ++m) w[m] = (P[15] - P[m - 9]) + (hasR ? PR[m - 8] : 0.f);
}

// Compute A,b row at vertical position j from a stage-1 set and accumulate
// scale*A into vA, scale*b into vB (scale folds validity mask / sign).
__device__ __forceinline__ void ab_accum(const float* __restrict__ Sx,
                                         const float* __restrict__ Sy,
                                         const float* __restrict__ Sxy,
                                         const float* __restrict__ Sxx,
                                         int lane, float invCR, float scale,
                                         float* __restrict__ vA,
                                         float* __restrict__ vB) {
    float w[16], mx[16], my[16], cv[16];
    win17_nbr(Sx, lane, w);
#pragma unroll
    for (int m = 0; m < 16; ++m) mx[m] = w[m] * (invCR * invCCf(lane, m));
    win17_nbr(Sy, lane, w);
#pragma unroll
    for (int m = 0; m < 16; ++m) my[m] = w[m] * (invCR * invCCf(lane, m));
    win17_nbr(Sxy, lane, w);
#pragma unroll
    for (int m = 0; m < 16; ++m)
        cv[m] = w[m] * (invCR * invCCf(lane, m)) - mx[m] * my[m];
    win17_nbr(Sxx, lane, w);
#pragma unroll
    for (int m = 0; m < 16; ++m) {
        float vr = w[m] * (invCR * invCCf(lane, m)) - mx[m] * mx[m];
        float A  = cv[m] / (vr + 1e-8f);
        vA[m] = fmaf(scale, A, vA[m]);
        vB[m] = fmaf(scale, my[m] - A * mx[m], vB[m]);
    }
}

__global__ __launch_bounds__(64)
void fgf_one(const float* __restrict__ x, const float* __restrict__ y,
             float* __restrict__ out)
{
    const int lane  = threadIdx.x;
    const int chunk = blockIdx.x;
    const int p  = chunk / NCHROW;
    const int R0 = (chunk - p * NCHROW) * CH;
    const size_t po = (size_t)p * HH * WW;
    const float* xp = x + po;
    const float* yp = y + po;
    float* op = out + po;

    float Lx[16], Ly[16], Lxy[16], Lxx[16];   // lead stage-1 set
    float Tx[16], Ty[16], Txy[16], Txx[16];   // trail stage-1 set (lags 17)
    float vA[16], vB[16];                     // vertical A,b running sums
#pragma unroll
    for (int m = 0; m < 16; ++m) {
        Lx[m] = Ly[m] = Lxy[m] = Lxx[m] = 0.f;
        Tx[m] = Ty[m] = Txy[m] = Txx[m] = 0.f;
        vA[m] = vB[m] = 0.f;
    }

    // ---- init: rows [R0-18, R0-1] ∩ [0,H).
    // lead window (pos R0-9) covers rows [R0-17, R0-1];
    // trail window (pos R0-10) covers rows [R0-18, R0-2].
    {
        const int rlo = (R0 - 18 > 0) ? (R0 - 18) : 0;
#pragma unroll 1
        for (int r = rlo; r < R0; ++r) {
            float xv[16], yv[16];
            load16(xp + (size_t)r * WW, lane, xv);
            load16(yp + (size_t)r * WW, lane, yv);
            const float ml = (r >= R0 - 17) ? 1.f : 0.f;
            const float mt = (r <= R0 - 2)  ? 1.f : 0.f;
#pragma unroll
            for (int m = 0; m < 16; ++m) {
                float a = ml * xv[m], b = ml * yv[m];
                Lx[m] += a; Ly[m] += b;
                Lxy[m] = fmaf(a, yv[m], Lxy[m]);
                Lxx[m] = fmaf(a, xv[m], Lxx[m]);
                float c = mt * xv[m], d = mt * yv[m];
                Tx[m] += c; Ty[m] += d;
                Txy[m] = fmaf(c, yv[m], Txy[m]);
                Txx[m] = fmaf(c, xv[m], Txx[m]);
            }
        }
    }

    // ---- A-warm: j = R0-8 .. R0+7; lead slides to pos j; vA += A(j) (j>=0).
#pragma unroll 1
    for (int j = R0 - RAD; j < R0 + RAD; ++j) {
        const int ra = j + RAD;
        const float sa = (ra < HH) ? 1.f : 0.f;
        const int ras = (ra < HH) ? ra : (HH - 1);
        const int rb = j - RAD - 1;
        const float sb = (rb >= 0) ? 1.f : 0.f;
        const int rbs = (rb >= 0) ? rb : 0;
        float xa[16], ya[16], xb[16], yb[16];
        load16(xp + (size_t)ras * WW, lane, xa);
        load16(yp + (size_t)ras * WW, lane, ya);
        load16(xp + (size_t)rbs * WW, lane, xb);
        load16(yp + (size_t)rbs * WW, lane, yb);
#pragma unroll
        for (int m = 0; m < 16; ++m) {
            float a = sa * xa[m], b = sa * ya[m];
            float c = sb * xb[m], d = sb * yb[m];
            Lx[m] += a - c; Ly[m] += b - d;
            Lxy[m] = fmaf(a, ya[m], Lxy[m]); Lxy[m] = fmaf(-c, yb[m], Lxy[m]);
            Lxx[m] = fmaf(a, xa[m], Lxx[m]); Lxx[m] = fmaf(-c, xb[m], Lxx[m]);
        }
        if (j >= 0) {
            ab_accum(Lx, Ly, Lxy, Lxx, lane, invCRf(j), 1.f, vA, vB);
        }
    }

    // ---- main: t = 0..CH-1, output row i = R0+t.
#pragma unroll 1
    for (int t = 0; t < CH; ++t) {
        const int i  = R0 + t;
        const int jl = i + RAD;              // lead A-row
        const int jt = i - RAD - 1;          // trail A-row
        const int ra = i + 2 * RAD;          // lead add x-row
        const int rb = i - 1;                // SHARED: lead sub + trail add
        const int rc = i - 2 * (RAD + 1);    // trail sub x-row (i-18)
        const float sa = (ra < HH) ? 1.f : 0.f;
        const int ras = (ra < HH) ? ra : (HH - 1);
        const float sb = (rb >= 0) ? 1.f : 0.f;
        const int rbs = (rb >= 0) ? rb : 0;
        const float sc = (rc >= 0) ? 1.f : 0.f;
        const int rcs = (rc >= 0) ? rc : 0;

        // phase 1: slide lead (add ra, sub rb) and trail (add rb, sub rc)
        {
            float xa[16], ya[16], xb[16], yb[16];
            load16(xp + (size_t)ras * WW, lane, xa);
            load16(yp + (size_t)ras * WW, lane, ya);
            load16(xp + (size_t)rbs * WW, lane, xb);
            load16(yp + (size_t)rbs * WW, lane, yb);
#pragma unroll
            for (int m = 0; m < 16; ++m) {
                float a = sa * xa[m], b = sa * ya[m];
                float c = sb * xb[m], d = sb * yb[m];
                Lx[m] += a - c; Ly[m] += b - d;
                Lxy[m] = fmaf(a, ya[m], Lxy[m]); Lxy[m] = fmaf(-c, yb[m], Lxy[m]);
                Lxx[m] = fmaf(a, xa[m], Lxx[m]); Lxx[m] = fmaf(-c, xb[m], Lxx[m]);
                Tx[m] += c; Ty[m] += d;
                Txy[m] = fmaf(c, yb[m], Txy[m]);
                Txx[m] = fmaf(c, xb[m], Txx[m]);
            }
            float xc[16], yc[16];
            load16(xp + (size_t)rcs * WW, lane, xc);
            load16(yp + (size_t)rcs * WW, lane, yc);
#pragma unroll
            for (int m = 0; m < 16; ++m) {
                float e = sc * xc[m], f = sc * yc[m];
                Tx[m] -= e; Ty[m] -= f;
                Txy[m] = fmaf(-e, yc[m], Txy[m]);
                Txx[m] = fmaf(-e, xc[m], Txx[m]);
            }
        }
        // phase 2: lead A,b(jl) -> vA,vB (+; masked if jl >= H)
        {
            const float la = (jl < HH) ? 1.f : 0.f;
            ab_accum(Lx, Ly, Lxy, Lxx, lane, invCRf(jl), la, vA, vB);
        }
        // phase 3: trail A,b(jt) -> vA,vB (-) — wave-uniform branch; A-row jt
        // was only ever added when t>=1 and jt>=0.
        if (t >= 1 && jt >= 0) {
            ab_accum(Tx, Ty, Txy, Txx, lane, invCRf(jt), -1.f, vA, vB);
        }
        // phase 4: output row i
        {
            const float invCR = invCRf(i);
            float wA[16], wB[16], xv[16];
            win17_nbr(vA, lane, wA);
            win17_nbr(vB, lane, wB);
            load16(xp + (size_t)i * WW, lane, xv);
            float4* Orow = (float4*)(op + (size_t)i * WW) + lane * 4;
#pragma unroll
            for (int k = 0; k < 4; ++k) {
                float4 o;
#pragma unroll
                for (int e = 0; e < 4; ++e) {
                    const int m = 4 * k + e;
                    float invN = invCR * invCCf(lane, m);
                    ((float*)&o)[e] = fmaf(wA[m] * invN, xv[m], wB[m] * invN);
                }
                Orow[k] = o;
            }
        }
    }
}

extern "C" void kernel_launch(void* const* d_in, const int* in_sizes, int n_in,
                              void* d_out, int out_size, void* d_ws, size_t ws_size,
                              hipStream_t stream) {
    const float* x = (const float*)d_in[0];
    const float* y = (const float*)d_in[1];
    float* out = (float*)d_out;
    (void)d_ws; (void)ws_size; (void)in_sizes; (void)n_in; (void)out_size;

    fgf_one<<<dim3(NCHUNKS), 64, 0, stream>>>(x, y, out);
}